// Round 1
// baseline (429.449 us; speedup 1.0000x reference)
//
#include <hip/hip_runtime.h>
#include <math.h>

#define N_ENT 4096
#define BATCH 4
#define NHID  3
#define EMB   64
#define ALPHA 0.2f
#define MASK_FILL 9e-15f

// ---------------------------------------------------------------------------
// Kernel 1: h = ent_emb @ W  [4096,3]; src = h@a[:3]; dst = h@a[3:]
// ---------------------------------------------------------------------------
__global__ __launch_bounds__(256) void prep_kernel(
    const float* __restrict__ emb, const float* __restrict__ W,
    const float* __restrict__ a,
    float* __restrict__ h0G, float* __restrict__ h1G, float* __restrict__ h2G,
    float* __restrict__ dstG, float* __restrict__ srcG)
{
    int j = blockIdx.x * 256 + threadIdx.x;
    if (j >= N_ENT) return;
    const float* er = emb + (size_t)j * EMB;
    float h0 = 0.f, h1 = 0.f, h2 = 0.f;
    #pragma unroll
    for (int e = 0; e < EMB; ++e) {
        float v = er[e];
        h0 += v * W[e * 3 + 0];
        h1 += v * W[e * 3 + 1];
        h2 += v * W[e * 3 + 2];
    }
    h0G[j] = h0; h1G[j] = h1; h2G[j] = h2;
    srcG[j] = h0 * a[0] + h1 * a[1] + h2 * a[2];
    dstG[j] = h0 * a[3] + h1 * a[4] + h2 * a[5];
}

// ---------------------------------------------------------------------------
// Kernel 2: per (b,i) row — exact two-pass masked softmax fused with att@h,
// then ELU. One wave per row; h/dst staged in LDS (64 KB -> 2 blocks/CU).
// ---------------------------------------------------------------------------
__global__ __launch_bounds__(256, 2) void gat_row_kernel(
    const int* __restrict__ adj,
    const float* __restrict__ h0G, const float* __restrict__ h1G,
    const float* __restrict__ h2G, const float* __restrict__ dstG,
    const float* __restrict__ srcG, float* __restrict__ xG)
{
    __shared__ float dstL[N_ENT];
    __shared__ float h0L[N_ENT];
    __shared__ float h1L[N_ENT];
    __shared__ float h2L[N_ENT];

    int tid = threadIdx.x;
    for (int t = tid; t < N_ENT; t += 256) {
        dstL[t] = dstG[t];
        h0L[t]  = h0G[t];
        h1L[t]  = h1G[t];
        h2L[t]  = h2G[t];
    }
    __syncthreads();

    int lane = tid & 63;
    int gw   = blockIdx.x * 4 + (tid >> 6);   // global wave id, 0..2047

    for (int r = 0; r < 8; ++r) {
        int row = gw * 8 + r;                 // row = b*N_ENT + i, 0..16383
        int i   = row & (N_ENT - 1);
        float src = srcG[i];
        const int4* arow = (const int4*)(adj + (size_t)row * N_ENT);

        // ---- issue all 16 adjacency int4 loads up-front (MLP) ----
        int4 av[16];
        #pragma unroll
        for (int c = 0; c < 16; ++c) av[c] = arow[c * 64 + lane];

        // ---- pass 1: compute logits, track row max ----
        float vals[64];
        float m = -3.4e38f;
        #pragma unroll
        for (int c = 0; c < 16; ++c) {
            int jb = (c * 64 + lane) * 4;
            float4 d4 = *(const float4*)&dstL[jb];
            float t0 = src + d4.x, t1 = src + d4.y, t2 = src + d4.z, t3 = src + d4.w;
            // leaky_relu(x) = max(x, 0.2x)
            float v0 = av[c].x > 0 ? fmaxf(t0, ALPHA * t0) : MASK_FILL;
            float v1 = av[c].y > 0 ? fmaxf(t1, ALPHA * t1) : MASK_FILL;
            float v2 = av[c].z > 0 ? fmaxf(t2, ALPHA * t2) : MASK_FILL;
            float v3 = av[c].w > 0 ? fmaxf(t3, ALPHA * t3) : MASK_FILL;
            vals[c * 4 + 0] = v0; vals[c * 4 + 1] = v1;
            vals[c * 4 + 2] = v2; vals[c * 4 + 3] = v3;
            m = fmaxf(m, fmaxf(fmaxf(v0, v1), fmaxf(v2, v3)));
        }
        #pragma unroll
        for (int off = 32; off; off >>= 1)
            m = fmaxf(m, __shfl_xor(m, off, 64));

        // ---- pass 2: exp + weighted accumulation over h (F=3) ----
        float l = 0.f, n0 = 0.f, n1 = 0.f, n2 = 0.f;
        #pragma unroll
        for (int c = 0; c < 16; ++c) {
            int jb = (c * 64 + lane) * 4;
            float4 a0 = *(const float4*)&h0L[jb];
            float4 a1 = *(const float4*)&h1L[jb];
            float4 a2 = *(const float4*)&h2L[jb];
            float p0 = __expf(vals[c * 4 + 0] - m);
            float p1 = __expf(vals[c * 4 + 1] - m);
            float p2 = __expf(vals[c * 4 + 2] - m);
            float p3 = __expf(vals[c * 4 + 3] - m);
            l  += (p0 + p1) + (p2 + p3);
            n0 += p0 * a0.x + p1 * a0.y + p2 * a0.z + p3 * a0.w;
            n1 += p0 * a1.x + p1 * a1.y + p2 * a1.z + p3 * a1.w;
            n2 += p0 * a2.x + p1 * a2.y + p2 * a2.z + p3 * a2.w;
        }
        #pragma unroll
        for (int off = 32; off; off >>= 1) {
            l  += __shfl_xor(l,  off, 64);
            n0 += __shfl_xor(n0, off, 64);
            n1 += __shfl_xor(n1, off, 64);
            n2 += __shfl_xor(n2, off, 64);
        }

        if (lane == 0) {
            float inv = 1.f / l;
            float hp0 = n0 * inv, hp1 = n1 * inv, hp2 = n2 * inv;
            float* xp = xG + (size_t)row * 3;
            xp[0] = hp0 > 0.f ? hp0 : expm1f(hp0);   // ELU (alpha=1)
            xp[1] = hp1 > 0.f ? hp1 : expm1f(hp1);
            xp[2] = hp2 > 0.f ? hp2 : expm1f(hp2);
        }
    }
}

// ---------------------------------------------------------------------------
// Kernel 3: out[b,k] = x[b,:] . fc1_w[k,:] + fc1_b[k].  One block per k,
// 4 batch accumulators so each weight row is read once.
// ---------------------------------------------------------------------------
__global__ __launch_bounds__(256) void fc_kernel(
    const float* __restrict__ xG, const float* __restrict__ w,
    const float* __restrict__ bias, float* __restrict__ out)
{
    int k   = blockIdx.x;           // 0..99
    int tid = threadIdx.x;
    const float4* wr = (const float4*)(w + (size_t)k * (N_ENT * NHID));
    const float4* x0 = (const float4*)(xG + 0 * (N_ENT * NHID));
    const float4* x1 = (const float4*)(xG + 1 * (N_ENT * NHID));
    const float4* x2 = (const float4*)(xG + 2 * (N_ENT * NHID));
    const float4* x3 = (const float4*)(xG + 3 * (N_ENT * NHID));

    float acc0 = 0.f, acc1 = 0.f, acc2 = 0.f, acc3 = 0.f;
    for (int t = tid; t < (N_ENT * NHID / 4); t += 256) {   // 3072/256 = 12 iters
        float4 wv = wr[t];
        float4 xv;
        xv = x0[t]; acc0 += wv.x*xv.x + wv.y*xv.y + wv.z*xv.z + wv.w*xv.w;
        xv = x1[t]; acc1 += wv.x*xv.x + wv.y*xv.y + wv.z*xv.z + wv.w*xv.w;
        xv = x2[t]; acc2 += wv.x*xv.x + wv.y*xv.y + wv.z*xv.z + wv.w*xv.w;
        xv = x3[t]; acc3 += wv.x*xv.x + wv.y*xv.y + wv.z*xv.z + wv.w*xv.w;
    }

    #pragma unroll
    for (int off = 32; off; off >>= 1) {
        acc0 += __shfl_xor(acc0, off, 64);
        acc1 += __shfl_xor(acc1, off, 64);
        acc2 += __shfl_xor(acc2, off, 64);
        acc3 += __shfl_xor(acc3, off, 64);
    }

    __shared__ float red[4][4];     // [wave][batch]
    int lane = tid & 63, wv_ = tid >> 6;
    if (lane == 0) {
        red[wv_][0] = acc0; red[wv_][1] = acc1;
        red[wv_][2] = acc2; red[wv_][3] = acc3;
    }
    __syncthreads();
    if (tid < 4) {   // tid = batch index
        float s = red[0][tid] + red[1][tid] + red[2][tid] + red[3][tid] + bias[k];
        out[tid * 100 + k] = s;
    }
}

// ---------------------------------------------------------------------------
extern "C" void kernel_launch(void* const* d_in, const int* in_sizes, int n_in,
                              void* d_out, int out_size, void* d_ws, size_t ws_size,
                              hipStream_t stream)
{
    const int*   adj  = (const int*)d_in[0];
    const float* emb  = (const float*)d_in[1];
    const float* W    = (const float*)d_in[2];
    const float* a    = (const float*)d_in[3];
    const float* fc1w = (const float*)d_in[4];
    const float* fc1b = (const float*)d_in[5];
    float* out = (float*)d_out;

    float* ws   = (float*)d_ws;
    float* h0G  = ws;               // 4096
    float* h1G  = ws + 4096;        // 4096
    float* h2G  = ws + 8192;        // 4096
    float* dstG = ws + 12288;       // 4096
    float* srcG = ws + 16384;       // 4096
    float* xG   = ws + 20480;       // 4*4096*3 = 49152

    prep_kernel<<<N_ENT / 256, 256, 0, stream>>>(emb, W, a, h0G, h1G, h2G, dstG, srcG);
    gat_row_kernel<<<512, 256, 0, stream>>>(adj, h0G, h1G, h2G, dstG, srcG, xG);
    fc_kernel<<<100, 256, 0, stream>>>(xG, fc1w, fc1b, out);
}